// Round 9
// baseline (329.005 us; speedup 1.0000x reference)
//
#include <hip/hip_runtime.h>
#include <math.h>

#define B_DIM 16
#define A_DIM 1024
#define V_DIM 512
#define D_DIM 512
#define NEGV  (-1e30f)
#define SKT_W 768   // skewT phys columns; pc = (c + off) mod 768 (injective/row)

typedef short bf16x8 __attribute__((ext_vector_type(8)));
typedef float floatx4 __attribute__((ext_vector_type(4)));

// round-to-nearest-even fp32 -> bf16
__device__ __forceinline__ short bf16_rne(float f) {
    unsigned u = __float_as_uint(f);
    return (short)((u + 0x7fffu + ((u >> 16) & 1u)) >> 16);
}

__device__ __forceinline__ float max3f(float a, float b, float c) {
    float d;
    asm("v_max3_f32 %0, %1, %2, %3" : "=v"(d) : "v"(a), "v"(b), "v"(c));
    return d;
}

// ---------------------------------------------------------------------------
// Merged elementwise fp32 -> bf16 for three segments (8 elems/thread).
// ---------------------------------------------------------------------------
__global__ __launch_bounds__(256) void cvt3_bf16_kernel(
    const float* __restrict__ in0, unsigned short* __restrict__ out0, int nb0,
    const float* __restrict__ in1, unsigned short* __restrict__ out1, int nb1,
    const float* __restrict__ in2, unsigned short* __restrict__ out2)
{
    int blk = blockIdx.x;
    const float* in; unsigned short* out;
    if (blk < nb0)              { in = in0; out = out0; }
    else if (blk < nb0 + nb1)   { in = in1; out = out1; blk -= nb0; }
    else                        { in = in2; out = out2; blk -= nb0 + nb1; }
    const int i = blk * 256 + threadIdx.x;
    float4 u = ((const float4*)in)[2*i];
    float4 v = ((const float4*)in)[2*i + 1];
    bf16x8 h;
    h[0]=bf16_rne(u.x); h[1]=bf16_rne(u.y); h[2]=bf16_rne(u.z); h[3]=bf16_rne(u.w);
    h[4]=bf16_rne(v.x); h[5]=bf16_rne(v.y); h[6]=bf16_rne(v.z); h[7]=bf16_rne(v.w);
    *(bf16x8*)(out + (size_t)i * 8) = h;
}

// ---------------------------------------------------------------------------
// bf16 MFMA NT GEMM tile body (128x128, BK=32, reg-prefetch K-pipeline).
// tid must be 0..255; all 256 lanes of the calling half participate.
// ---------------------------------------------------------------------------
__device__ __forceinline__ void gemm_tile_body(
    const unsigned short* __restrict__ Ab, const unsigned short* __restrict__ Bb,
    const float* __restrict__ bias, float* __restrict__ Cb,
    int m0, int n0, int K, int N, int tid,
    unsigned short* lA, unsigned short* lB)
{
    const int lane = tid & 63;
    const int w = tid >> 6, wy = w >> 1, wx = w & 1;

    const int u0 = tid, u1 = tid + 256;
    const int r_u0 = ((u0 >> 6) << 4) + (u0 & 15), k_u0 = ((u0 >> 4) & 3) * 8;
    const int r_u1 = ((u1 >> 6) << 4) + (u1 & 15), k_u1 = ((u1 >> 4) & 3) * 8;

    const unsigned short* gA0 = Ab + (size_t)(m0 + r_u0) * K + k_u0;
    const unsigned short* gA1 = Ab + (size_t)(m0 + r_u1) * K + k_u1;
    const unsigned short* gB0 = Bb + (size_t)(n0 + r_u0) * K + k_u0;
    const unsigned short* gB1 = Bb + (size_t)(n0 + r_u1) * K + k_u1;

    floatx4 acc[4][4];
    #pragma unroll
    for (int i = 0; i < 4; ++i)
        #pragma unroll
        for (int j = 0; j < 4; ++j) acc[i][j] = (floatx4){0.f, 0.f, 0.f, 0.f};

    bf16x8 a0 = *(const bf16x8*)(gA0);
    bf16x8 a1 = *(const bf16x8*)(gA1);
    bf16x8 b0 = *(const bf16x8*)(gB0);
    bf16x8 b1 = *(const bf16x8*)(gB1);

    for (int k0 = 0; k0 < K; k0 += 32) {
        __syncthreads();
        *(bf16x8*)&lA[(size_t)u0 * 8] = a0;
        *(bf16x8*)&lA[(size_t)u1 * 8] = a1;
        *(bf16x8*)&lB[(size_t)u0 * 8] = b0;
        *(bf16x8*)&lB[(size_t)u1 * 8] = b1;
        __syncthreads();

        if (k0 + 32 < K) {
            a0 = *(const bf16x8*)(gA0 + k0 + 32);
            a1 = *(const bf16x8*)(gA1 + k0 + 32);
            b0 = *(const bf16x8*)(gB0 + k0 + 32);
            b1 = *(const bf16x8*)(gB1 + k0 + 32);
        }

        bf16x8 fa[4], fb[4];
        #pragma unroll
        for (int t = 0; t < 4; ++t) {
            fa[t] = *(const bf16x8*)&lA[(((wy*4 + t)*64) + lane) * 8];
            fb[t] = *(const bf16x8*)&lB[(((wx*4 + t)*64) + lane) * 8];
        }
        #pragma unroll
        for (int i = 0; i < 4; ++i)
            #pragma unroll
            for (int j = 0; j < 4; ++j)
                acc[i][j] = __builtin_amdgcn_mfma_f32_16x16x32_bf16(fa[i], fb[j], acc[i][j], 0, 0, 0);
    }

    const int q = lane >> 4, c = lane & 15;
    #pragma unroll
    for (int i = 0; i < 4; ++i)
        #pragma unroll
        for (int j = 0; j < 4; ++j) {
            const int n = n0 + (wx*4 + j)*16 + c;
            const float bv = bias ? bias[n] : 0.f;
            #pragma unroll
            for (int r = 0; r < 4; ++r) {
                const int m = m0 + (wy*4 + i)*16 + q*4 + r;
                Cb[(size_t)m * N + n] = acc[i][j][r] + bv;
            }
        }
}

// sim GEMM (batched NT).
__global__ __launch_bounds__(256) void gemm_bf16_nt(
    const unsigned short* __restrict__ Ag, const unsigned short* __restrict__ Bg,
    const float* __restrict__ bias, float* __restrict__ Cg,
    int M, int N, int K, size_t strA, size_t strB, size_t strC)
{
    __shared__ __align__(16) unsigned short lA[8*64*8];
    __shared__ __align__(16) unsigned short lB[8*64*8];
    const unsigned short* Ab = Ag + (size_t)blockIdx.z * strA;
    const unsigned short* Bb = Bg + (size_t)blockIdx.z * strB;
    float*                Cb = Cg + (size_t)blockIdx.z * strC;
    gemm_tile_body(Ab, Bb, bias, Cb, blockIdx.y * 128, blockIdx.x * 128, K, N,
                   threadIdx.x, lA, lB);
}

// Merged projections: audio (by<128) and video (by>=128) in one launch.
__global__ __launch_bounds__(256) void gemm_proj2(
    const unsigned short* __restrict__ abf, const unsigned short* __restrict__ vbf,
    const unsigned short* __restrict__ Wbf, const float* __restrict__ bias,
    float* __restrict__ a_p, float* __restrict__ v_p)
{
    __shared__ __align__(16) unsigned short lA[8*64*8];
    __shared__ __align__(16) unsigned short lB[8*64*8];
    const int by = blockIdx.y;
    const unsigned short* Ab; float* Cb; int m0;
    if (by < 128) { Ab = abf; Cb = a_p; m0 = by * 128; }
    else          { Ab = vbf; Cb = v_p; m0 = (by - 128) * 128; }
    gemm_tile_body(Ab, Wbf, bias, Cb, m0, blockIdx.x * 128, D_DIM, D_DIM,
                   threadIdx.x, lA, lB);
}

// ---------------------------------------------------------------------------
// Merged: rownorm-a (blocks 0..4095), rownorm-v (4096..6143), 32x32
// transpose+cvt video->vT bf16 (6144..10239). Disjoint memory segments.
// ---------------------------------------------------------------------------
__global__ __launch_bounds__(256) void norm2_transpose_kernel(
    const float* __restrict__ a_p, unsigned short* __restrict__ a_nb,
    const float* __restrict__ v_p, unsigned short* __restrict__ v_nb,
    const float* __restrict__ video, unsigned short* __restrict__ vTb)
{
    __shared__ float t[32][33];
    const int bx = blockIdx.x;
    if (bx < 6144) {
        const float* in; unsigned short* out; int rb;
        if (bx < 4096) { in = a_p; out = a_nb; rb = bx; }
        else           { in = v_p; out = v_nb; rb = bx - 4096; }
        const int wave = threadIdx.x >> 6;
        const int lane = threadIdx.x & 63;
        const size_t r = (size_t)rb * 4 + wave;
        const float* p = in + r * D_DIM + lane * 8;
        float4 u = *(const float4*)p;
        float4 w = *(const float4*)(p + 4);
        float ss = u.x*u.x + u.y*u.y + u.z*u.z + u.w*u.w
                 + w.x*w.x + w.y*w.y + w.z*w.z + w.w*w.w;
        #pragma unroll
        for (int m = 1; m < 64; m <<= 1) ss += __shfl_xor(ss, m, 64);
        const float inv = 1.0f / fmaxf(sqrtf(ss), 1e-12f);
        bf16x8 h;
        h[0]=bf16_rne(u.x*inv); h[1]=bf16_rne(u.y*inv); h[2]=bf16_rne(u.z*inv); h[3]=bf16_rne(u.w*inv);
        h[4]=bf16_rne(w.x*inv); h[5]=bf16_rne(w.y*inv); h[6]=bf16_rne(w.z*inv); h[7]=bf16_rne(w.w*inv);
        *(bf16x8*)(out + r * D_DIM + lane * 8) = h;
    } else {
        const int tt = bx - 6144;
        const int d0 = (tt & 15) * 32;
        const int v0 = ((tt >> 4) & 15) * 32;
        const int b  = tt >> 8;
        const int x = threadIdx.x & 31, y0 = (threadIdx.x >> 5) * 4;
        const float* I = video + ((size_t)b * V_DIM + v0) * D_DIM + d0;
        #pragma unroll
        for (int r = 0; r < 4; ++r) t[y0 + r][x] = I[(size_t)(y0 + r) * D_DIM + x];
        __syncthreads();
        unsigned short* O = vTb + ((size_t)b * D_DIM + d0) * V_DIM + v0;
        #pragma unroll
        for (int r = 0; r < 4; ++r) O[(size_t)(y0 + r) * V_DIM + x] = (unsigned short)bf16_rne(t[x][y0 + r]);
    }
}

// ---------------------------------------------------------------------------
// DPP helper (wave64). 0x138 = wave_shr:1 (lane l <- l-1; lane 0 keeps oldv
// with bound_ctrl=false). Verified in prior rounds.
// ---------------------------------------------------------------------------
template <int CTRL, int RMASK>
__device__ __forceinline__ float fdpp(float oldv, float src) {
    int r = __builtin_amdgcn_update_dpp(
        __float_as_int(oldv), __float_as_int(src), CTRL, RMASK, 0xF, false);
    return __int_as_float(r);
}

// ---------------------------------------------------------------------------
// Fused: row softmax -> Pbf (bf16) + COLUMN-MAJOR skewed fp32 sim copy:
// skewT[b][(c + off) % 768][i] = sim[b][i][c], off(i) = ((i>>2)&63) + 80*(i>>8)
// (systolic quad g = i>>2 owned by lane g&63 of wave g>>6, E=80 wave gap).
// Quad-aligned blocks -> same off -> contiguous 16B runs via LDS transpose.
// Mod-768 wrap is injective per row; the DTW jj<512 guard selects valid c.
// ---------------------------------------------------------------------------
__global__ __launch_bounds__(256) void softmax_skewT_kernel(
    const float* __restrict__ sim, unsigned short* __restrict__ Pbf,
    float* __restrict__ skewT)
{
    __shared__ float tl[4][520];
    const int wave = threadIdx.x >> 6;
    const int lane = threadIdx.x & 63;
    const size_t r = (size_t)blockIdx.x * 4 + wave;
    const float* p = sim + r * V_DIM + lane * 8;
    float4 u = *(const float4*)p;
    float4 w = *(const float4*)(p + 4);
    float s[8] = {u.x,u.y,u.z,u.w,w.x,w.y,w.z,w.w};

    float m = s[0];
    #pragma unroll
    for (int k = 1; k < 8; ++k) m = fmaxf(m, s[k]);
    #pragma unroll
    for (int t = 1; t < 64; t <<= 1) m = fmaxf(m, __shfl_xor(m, t, 64));

    const float L2E = 1.44269504f;
    float ex[8];
    float e = 0.f;
    #pragma unroll
    for (int k = 0; k < 8; ++k) { ex[k] = exp2f((s[k] - m) * L2E); e += ex[k]; }
    #pragma unroll
    for (int t = 1; t < 64; t <<= 1) e += __shfl_xor(e, t, 64);
    const float ri = 1.0f / e;

    bf16x8 h;
    #pragma unroll
    for (int k = 0; k < 8; ++k) h[k] = bf16_rne(ex[k] * ri);
    *(bf16x8*)(Pbf + r * V_DIM + lane * 8) = h;

    // stash raw sim rows in LDS, write transposed 16B runs
    #pragma unroll
    for (int k = 0; k < 8; ++k) tl[wave][lane * 8 + k] = s[k];
    __syncthreads();

    const int r0 = blockIdx.x * 4;
    const int b  = r0 >> 10;
    const int i0 = r0 & 1023;
    const int g  = i0 >> 2;
    const int off = (g & 63) + 80 * (g >> 6);
    float* sbase = skewT + (size_t)b * SKT_W * 1024 + i0;
    #pragma unroll
    for (int cc = 0; cc < 2; ++cc) {
        const int c = threadIdx.x + cc * 256;
        int pc = c + off; if (pc >= SKT_W) pc -= SKT_W;
        float4 v = make_float4(tl[0][c], tl[1][c], tl[2][c], tl[3][c]);
        *(float4*)(sbase + (size_t)pc * 1024) = v;
    }
}

// ---------------------------------------------------------------------------
// Fused PV GEMM + wavefront DTW, 512-thread blocks (two problems/tiles per
// block so 8 waves/CU = 2/SIMD interleave the serial dep chains).
// DTW (blocks 0..7, half h handles batch b=2*blk+h): 256-lane systolic per
// half, lane g owns rows 4g..4g+3, off = (g&63) + 80*(g>>6); barrier once per
// 16-step batch (E-64=16 slack); boundary rows via per-wave 528-slot LDS
// write-once arrays (NEG prefill, [0,7) never written = neg fills, dump 527).
// 4 register buffers = 32 columns in flight (refill sb+32..47). Coalesced
// column loads from skewT (1KB contiguous per wave per step).
// ---------------------------------------------------------------------------
__global__ __launch_bounds__(512) void pv_dtw_kernel(
    const unsigned short* __restrict__ Pbf, const unsigned short* __restrict__ vTb,
    const float* __restrict__ skewT, float* __restrict__ out_aligned,
    float* __restrict__ out_score)
{
    __shared__ __align__(16) unsigned short shmem_u16[16384];   // 32 KB

    const int half = threadIdx.x >> 8;
    const int tid  = threadIdx.x & 255;

    if (blockIdx.x < 8) {
        // ---------------- DTW path (two batches per block) ----------------
        const int b    = blockIdx.x * 2 + half;
        const int lane = tid & 63;
        const int wv   = tid >> 6;
        const int off  = lane + 80 * wv;

        float* bndAll = (float*)shmem_u16 + half * (3 * 528);
        float* bndP = bndAll + wv * 528;
        const float* bndC = bndAll + (wv > 0 ? wv - 1 : 0) * 528;
        for (int i = tid; i < 3 * 528; i += 256) bndAll[i] = NEGV;
        __syncthreads();

        const float* Sb = skewT + (size_t)b * SKT_W * 1024 + 4 * tid;

        float dp[4] = {NEGV, NEGV, NEGV, NEGV};
        float st[16];
        float upC = NEGV;
        float upL = (tid == 0) ? 0.0f : NEGV;

        float4 CA[8], CB[8], CC[8], CD[8];
        #pragma unroll
        for (int k = 0; k < 8; ++k) {
            CA[k] = *(const float4*)(Sb + (size_t)k * 1024);
            CB[k] = *(const float4*)(Sb + (size_t)(k + 8) * 1024);
            CC[k] = *(const float4*)(Sb + (size_t)(k + 16) * 1024);
            CD[k] = *(const float4*)(Sb + (size_t)(k + 24) * 1024);
        }

// one systolic step (K compile-time). Cell math verified R5/R8.
#define DTW_STEP(K, CK, FK)                                                   \
        {                                                                     \
            const unsigned jj = (unsigned)(sb + (K) - off);                   \
            if (jj < 512u) {                                                  \
                float u = upC, g = upL, old, nd;                              \
                old = dp[0]; nd = (CK).x + max3f(u, dp[0], g); dp[0] = nd; g = old; u = nd; \
                old = dp[1]; nd = (CK).y + max3f(u, dp[1], g); dp[1] = nd; g = old; u = nd; \
                old = dp[2]; nd = (CK).z + max3f(u, dp[2], g); dp[2] = nd; g = old; u = nd; \
                old = dp[3]; nd = (CK).w + max3f(u, dp[3], g); dp[3] = nd;                  \
            }                                                                 \
            st[K] = dp[3];                                                    \
            upL = upC;                                                        \
            upC = fdpp<0x138, 0xF>((FK), dp[3]);                              \
        }

// one 16-step batch on buffers P,Q; refill P,Q <- cols sb+32..47; barrier.
// Fill address for step sb+K: idx = sb+K+8-80*wv (+1 next-step, +7 bias),
// clamped per element ([0,7) = NEG prefill for cols<0; 527 dump for cols>=512
// whose cells are predicated off anyway).
#define DTW_BATCH16(P, Q)                                                     \
        {                                                                     \
            const int ps = sb + 8 - 80 * wv;                                  \
            float f[16];                                                      \
            _Pragma("unroll")                                                 \
            for (int k = 0; k < 16; ++k) {                                    \
                int idx = ps + k;                                             \
                idx = idx < 0 ? 0 : (idx > 527 ? 527 : idx);                  \
                f[k] = (wv > 0) ? bndC[idx] : NEGV;                           \
            }                                                                 \
            DTW_STEP(0,  P[0], f[0])  DTW_STEP(1,  P[1], f[1])                \
            DTW_STEP(2,  P[2], f[2])  DTW_STEP(3,  P[3], f[3])                \
            DTW_STEP(4,  P[4], f[4])  DTW_STEP(5,  P[5], f[5])                \
            DTW_STEP(6,  P[6], f[6])  DTW_STEP(7,  P[7], f[7])                \
            DTW_STEP(8,  Q[0], f[8])  DTW_STEP(9,  Q[1], f[9])                \
            DTW_STEP(10, Q[2], f[10]) DTW_STEP(11, Q[3], f[11])               \
            DTW_STEP(12, Q[4], f[12]) DTW_STEP(13, Q[5], f[13])               \
            DTW_STEP(14, Q[6], f[14]) DTW_STEP(15, Q[7], f[15])               \
            {                                                                 \
                _Pragma("unroll")                                             \
                for (int k = 0; k < 8; ++k) {                                 \
                    int c1 = sb + 32 + k; if (c1 >= SKT_W) c1 -= SKT_W;       \
                    P[k] = *(const float4*)(Sb + (size_t)c1 * 1024);          \
                    int c2 = sb + 40 + k; if (c2 >= SKT_W) c2 -= SKT_W;       \
                    Q[k] = *(const float4*)(Sb + (size_t)c2 * 1024);          \
                }                                                             \
            }                                                                 \
            if (wv < 3 && lane == 63) {                                       \
                _Pragma("unroll")                                             \
                for (int k = 0; k < 16; ++k) {                                \
                    const int jp = sb + k - 63 - 80 * wv;                     \
                    const int adr = ((unsigned)jp < 512u) ? (jp + 7) : 527;   \
                    bndP[adr] = st[k];                                        \
                }                                                             \
            }                                                                 \
            asm volatile("s_waitcnt lgkmcnt(0)" ::: "memory");                \
            __builtin_amdgcn_s_barrier();                                     \
            asm volatile("" ::: "memory");                                    \
        }

        #pragma unroll 1
        for (int bt = 0; bt < 52; bt += 2) {
            int sb = bt * 16;
            DTW_BATCH16(CA, CB)
            sb += 16;
            DTW_BATCH16(CC, CD)
        }
#undef DTW_BATCH16
#undef DTW_STEP
        if (tid == 255) out_score[b] = dp[3];   // row 1023, col 511 (t=814)
        return;
    }

    // ---------------- PV GEMM path (two 128x128 tiles per block) ----------
    const int tile = (blockIdx.x - 8) * 2 + half;   // 0..511
    const int n0 = (tile & 3) * 128;          // D/128 = 4
    const int m0 = ((tile >> 2) & 7) * 128;   // A/128 = 8
    const int bz = tile >> 5;                 // 16 batches

    const unsigned short* Ab = Pbf + (size_t)bz * A_DIM * V_DIM;
    const unsigned short* Bb = vTb + (size_t)bz * V_DIM * D_DIM;
    float*                Cb = out_aligned + (size_t)bz * A_DIM * D_DIM;

    unsigned short* lA = shmem_u16 + half * 8192;
    unsigned short* lB = lA + 4096;
    gemm_tile_body(Ab, Bb, nullptr, Cb, m0, n0, V_DIM, D_DIM, tid, lA, lB);
}

// ---------------------------------------------------------------------------
extern "C" void kernel_launch(void* const* d_in, const int* in_sizes, int n_in,
                              void* d_out, int out_size, void* d_ws, size_t ws_size,
                              hipStream_t stream)
{
    const float* audio = (const float*)d_in[0];   // [16,1024,512]
    const float* video = (const float*)d_in[1];   // [16, 512,512]
    const float* W     = (const float*)d_in[2];   // [512,512]
    const float* bias  = (const float*)d_in[3];   // [512]

    float* out_aligned = (float*)d_out;
    float* out_score   = (float*)d_out + (size_t)B_DIM * A_DIM * D_DIM;

    const size_t NA = (size_t)B_DIM * A_DIM * D_DIM;   // 8.39M
    const size_t NV = (size_t)B_DIM * V_DIM * D_DIM;   // 4.19M
    const size_t NS = (size_t)B_DIM * A_DIM * V_DIM;   // 8.39M

    float* ws = (float*)d_ws;
    float*          a_p  = ws;                                 // NA fp32 [dead after norm-a]
    float*          v_p  = a_p + NA;                           // NV fp32 [dead after norm-v]
    float*          sim  = v_p + NV;                           // NS fp32
    unsigned short* abf  = (unsigned short*)(sim + NS);        // NA bf16 [dead after proj-a]
    unsigned short* vbf  = (unsigned short*)(sim + NS) + NA;   // NV bf16 [dead after proj-v]
    unsigned short* v_nb = vbf + NV;                           // NV bf16
    unsigned short* Wbf  = v_nb + NV;                          // 262144 bf16
    unsigned short* a_nb = abf;            // NA bf16 reuses dead abf (norm-a)
    unsigned short* Pbf  = abf;            // NS bf16 reuses a_nb (dead after sim GEMM)
    unsigned short* vTb  = vbf;            // NV bf16 reuses dead vbf
    // skewT: 16 x 768 x 1024 fp32 = 12.58M floats = a_p + v_p exactly.
    float*          skewT = a_p;

    // 1) fp32 -> bf16 input conversions, one merged launch
    {
        const int nb_a = (int)(NA / 8 / 256);             // 4096
        const int nb_v = (int)(NV / 8 / 256);             // 2048
        const int nb_w = D_DIM * D_DIM / 8 / 256;         // 128
        cvt3_bf16_kernel<<<dim3(nb_a + nb_v + nb_w), dim3(256), 0, stream>>>(
            audio, abf, nb_a, video, vbf, nb_v, W, Wbf);
    }

    // 2) merged projections: audio & video X @ W^T + b
    gemm_proj2<<<dim3(D_DIM/128, 192), dim3(256), 0, stream>>>(
        abf, vbf, Wbf, bias, a_p, v_p);

    // 3) merged rownorm-a + rownorm-v + video transpose
    norm2_transpose_kernel<<<dim3(4096 + 2048 + 4096), dim3(256), 0, stream>>>(
        a_p, a_nb, v_p, v_nb, video, vTb);

    // 4) sim[b] = a_n[b] @ v_n[b]^T
    gemm_bf16_nt<<<dim3(V_DIM/128, A_DIM/128, B_DIM), dim3(256), 0, stream>>>(
        a_nb, v_nb, nullptr, sim, A_DIM, V_DIM, D_DIM,
        (size_t)A_DIM*D_DIM, (size_t)V_DIM*D_DIM, (size_t)A_DIM*V_DIM);

    // 5) fused row softmax -> Pbf + column-major skewed sim copy for DTW
    softmax_skewT_kernel<<<dim3((B_DIM*A_DIM)/4), dim3(256), 0, stream>>>(sim, Pbf, skewT);

    // 6) fused PV GEMM + paired 16-step-batch coalesced DTW (512-thr blocks)
    pv_dtw_kernel<<<dim3(8 + 256), dim3(512), 0, stream>>>(
        Pbf, vTb, skewT, out_aligned, out_score);
}

// Round 10
// 268.700 us; speedup vs baseline: 1.2244x; 1.2244x over previous
//
#include <hip/hip_runtime.h>
#include <math.h>

#define B_DIM 16
#define A_DIM 1024
#define V_DIM 512
#define D_DIM 512
#define NEGV  (-1e30f)
#define SKT_W 768   // skewT phys columns; pc = (c + off) mod 768 (injective/row)

typedef short bf16x8 __attribute__((ext_vector_type(8)));
typedef float floatx4 __attribute__((ext_vector_type(4)));

// round-to-nearest-even fp32 -> bf16
__device__ __forceinline__ short bf16_rne(float f) {
    unsigned u = __float_as_uint(f);
    return (short)((u + 0x7fffu + ((u >> 16) & 1u)) >> 16);
}

__device__ __forceinline__ float max3f(float a, float b, float c) {
    float d;
    asm("v_max3_f32 %0, %1, %2, %3" : "=v"(d) : "v"(a), "v"(b), "v"(c));
    return d;
}

// ---------------------------------------------------------------------------
// Merged elementwise fp32 -> bf16 for three segments (8 elems/thread).
// ---------------------------------------------------------------------------
__global__ __launch_bounds__(256) void cvt3_bf16_kernel(
    const float* __restrict__ in0, unsigned short* __restrict__ out0, int nb0,
    const float* __restrict__ in1, unsigned short* __restrict__ out1, int nb1,
    const float* __restrict__ in2, unsigned short* __restrict__ out2)
{
    int blk = blockIdx.x;
    const float* in; unsigned short* out;
    if (blk < nb0)              { in = in0; out = out0; }
    else if (blk < nb0 + nb1)   { in = in1; out = out1; blk -= nb0; }
    else                        { in = in2; out = out2; blk -= nb0 + nb1; }
    const int i = blk * 256 + threadIdx.x;
    float4 u = ((const float4*)in)[2*i];
    float4 v = ((const float4*)in)[2*i + 1];
    bf16x8 h;
    h[0]=bf16_rne(u.x); h[1]=bf16_rne(u.y); h[2]=bf16_rne(u.z); h[3]=bf16_rne(u.w);
    h[4]=bf16_rne(v.x); h[5]=bf16_rne(v.y); h[6]=bf16_rne(v.z); h[7]=bf16_rne(v.w);
    *(bf16x8*)(out + (size_t)i * 8) = h;
}

// ---------------------------------------------------------------------------
// bf16 MFMA NT GEMM tile body (128x128, BK=32, reg-prefetch K-pipeline).
// ---------------------------------------------------------------------------
__device__ __forceinline__ void gemm_tile_body(
    const unsigned short* __restrict__ Ab, const unsigned short* __restrict__ Bb,
    const float* __restrict__ bias, float* __restrict__ Cb,
    int m0, int n0, int K, int N, int tid,
    unsigned short* lA, unsigned short* lB)
{
    const int lane = tid & 63;
    const int w = tid >> 6, wy = w >> 1, wx = w & 1;

    const int u0 = tid, u1 = tid + 256;
    const int r_u0 = ((u0 >> 6) << 4) + (u0 & 15), k_u0 = ((u0 >> 4) & 3) * 8;
    const int r_u1 = ((u1 >> 6) << 4) + (u1 & 15), k_u1 = ((u1 >> 4) & 3) * 8;

    const unsigned short* gA0 = Ab + (size_t)(m0 + r_u0) * K + k_u0;
    const unsigned short* gA1 = Ab + (size_t)(m0 + r_u1) * K + k_u1;
    const unsigned short* gB0 = Bb + (size_t)(n0 + r_u0) * K + k_u0;
    const unsigned short* gB1 = Bb + (size_t)(n0 + r_u1) * K + k_u1;

    floatx4 acc[4][4];
    #pragma unroll
    for (int i = 0; i < 4; ++i)
        #pragma unroll
        for (int j = 0; j < 4; ++j) acc[i][j] = (floatx4){0.f, 0.f, 0.f, 0.f};

    bf16x8 a0 = *(const bf16x8*)(gA0);
    bf16x8 a1 = *(const bf16x8*)(gA1);
    bf16x8 b0 = *(const bf16x8*)(gB0);
    bf16x8 b1 = *(const bf16x8*)(gB1);

    for (int k0 = 0; k0 < K; k0 += 32) {
        __syncthreads();
        *(bf16x8*)&lA[(size_t)u0 * 8] = a0;
        *(bf16x8*)&lA[(size_t)u1 * 8] = a1;
        *(bf16x8*)&lB[(size_t)u0 * 8] = b0;
        *(bf16x8*)&lB[(size_t)u1 * 8] = b1;
        __syncthreads();

        if (k0 + 32 < K) {
            a0 = *(const bf16x8*)(gA0 + k0 + 32);
            a1 = *(const bf16x8*)(gA1 + k0 + 32);
            b0 = *(const bf16x8*)(gB0 + k0 + 32);
            b1 = *(const bf16x8*)(gB1 + k0 + 32);
        }

        bf16x8 fa[4], fb[4];
        #pragma unroll
        for (int t = 0; t < 4; ++t) {
            fa[t] = *(const bf16x8*)&lA[(((wy*4 + t)*64) + lane) * 8];
            fb[t] = *(const bf16x8*)&lB[(((wx*4 + t)*64) + lane) * 8];
        }
        #pragma unroll
        for (int i = 0; i < 4; ++i)
            #pragma unroll
            for (int j = 0; j < 4; ++j)
                acc[i][j] = __builtin_amdgcn_mfma_f32_16x16x32_bf16(fa[i], fb[j], acc[i][j], 0, 0, 0);
    }

    const int q = lane >> 4, c = lane & 15;
    #pragma unroll
    for (int i = 0; i < 4; ++i)
        #pragma unroll
        for (int j = 0; j < 4; ++j) {
            const int n = n0 + (wx*4 + j)*16 + c;
            const float bv = bias ? bias[n] : 0.f;
            #pragma unroll
            for (int r = 0; r < 4; ++r) {
                const int m = m0 + (wy*4 + i)*16 + q*4 + r;
                Cb[(size_t)m * N + n] = acc[i][j][r] + bv;
            }
        }
}

// sim GEMM (batched NT).
__global__ __launch_bounds__(256) void gemm_bf16_nt(
    const unsigned short* __restrict__ Ag, const unsigned short* __restrict__ Bg,
    const float* __restrict__ bias, float* __restrict__ Cg,
    int M, int N, int K, size_t strA, size_t strB, size_t strC)
{
    __shared__ __align__(16) unsigned short lA[8*64*8];
    __shared__ __align__(16) unsigned short lB[8*64*8];
    const unsigned short* Ab = Ag + (size_t)blockIdx.z * strA;
    const unsigned short* Bb = Bg + (size_t)blockIdx.z * strB;
    float*                Cb = Cg + (size_t)blockIdx.z * strC;
    gemm_tile_body(Ab, Bb, bias, Cb, blockIdx.y * 128, blockIdx.x * 128, K, N,
                   threadIdx.x, lA, lB);
}

// Merged projections: audio (by<128) and video (by>=128) in one launch.
__global__ __launch_bounds__(256) void gemm_proj2(
    const unsigned short* __restrict__ abf, const unsigned short* __restrict__ vbf,
    const unsigned short* __restrict__ Wbf, const float* __restrict__ bias,
    float* __restrict__ a_p, float* __restrict__ v_p)
{
    __shared__ __align__(16) unsigned short lA[8*64*8];
    __shared__ __align__(16) unsigned short lB[8*64*8];
    const int by = blockIdx.y;
    const unsigned short* Ab; float* Cb; int m0;
    if (by < 128) { Ab = abf; Cb = a_p; m0 = by * 128; }
    else          { Ab = vbf; Cb = v_p; m0 = (by - 128) * 128; }
    gemm_tile_body(Ab, Wbf, bias, Cb, m0, blockIdx.x * 128, D_DIM, D_DIM,
                   threadIdx.x, lA, lB);
}

// ---------------------------------------------------------------------------
// Merged: rownorm-a (blocks 0..4095), rownorm-v (4096..6143), 32x32
// transpose+cvt video->vT bf16 (6144..10239). Disjoint memory segments.
// ---------------------------------------------------------------------------
__global__ __launch_bounds__(256) void norm2_transpose_kernel(
    const float* __restrict__ a_p, unsigned short* __restrict__ a_nb,
    const float* __restrict__ v_p, unsigned short* __restrict__ v_nb,
    const float* __restrict__ video, unsigned short* __restrict__ vTb)
{
    __shared__ float t[32][33];
    const int bx = blockIdx.x;
    if (bx < 6144) {
        const float* in; unsigned short* out; int rb;
        if (bx < 4096) { in = a_p; out = a_nb; rb = bx; }
        else           { in = v_p; out = v_nb; rb = bx - 4096; }
        const int wave = threadIdx.x >> 6;
        const int lane = threadIdx.x & 63;
        const size_t r = (size_t)rb * 4 + wave;
        const float* p = in + r * D_DIM + lane * 8;
        float4 u = *(const float4*)p;
        float4 w = *(const float4*)(p + 4);
        float ss = u.x*u.x + u.y*u.y + u.z*u.z + u.w*u.w
                 + w.x*w.x + w.y*w.y + w.z*w.z + w.w*w.w;
        #pragma unroll
        for (int m = 1; m < 64; m <<= 1) ss += __shfl_xor(ss, m, 64);
        const float inv = 1.0f / fmaxf(sqrtf(ss), 1e-12f);
        bf16x8 h;
        h[0]=bf16_rne(u.x*inv); h[1]=bf16_rne(u.y*inv); h[2]=bf16_rne(u.z*inv); h[3]=bf16_rne(u.w*inv);
        h[4]=bf16_rne(w.x*inv); h[5]=bf16_rne(w.y*inv); h[6]=bf16_rne(w.z*inv); h[7]=bf16_rne(w.w*inv);
        *(bf16x8*)(out + r * D_DIM + lane * 8) = h;
    } else {
        const int tt = bx - 6144;
        const int d0 = (tt & 15) * 32;
        const int v0 = ((tt >> 4) & 15) * 32;
        const int b  = tt >> 8;
        const int x = threadIdx.x & 31, y0 = (threadIdx.x >> 5) * 4;
        const float* I = video + ((size_t)b * V_DIM + v0) * D_DIM + d0;
        #pragma unroll
        for (int r = 0; r < 4; ++r) t[y0 + r][x] = I[(size_t)(y0 + r) * D_DIM + x];
        __syncthreads();
        unsigned short* O = vTb + ((size_t)b * D_DIM + d0) * V_DIM + v0;
        #pragma unroll
        for (int r = 0; r < 4; ++r) O[(size_t)(y0 + r) * V_DIM + x] = (unsigned short)bf16_rne(t[x][y0 + r]);
    }
}

// ---------------------------------------------------------------------------
// DPP helper (wave64). 0x138 = wave_shr:1 (lane l <- l-1; lane 0 keeps oldv
// with bound_ctrl=false). Verified in prior rounds.
// ---------------------------------------------------------------------------
template <int CTRL, int RMASK>
__device__ __forceinline__ float fdpp(float oldv, float src) {
    int r = __builtin_amdgcn_update_dpp(
        __float_as_int(oldv), __float_as_int(src), CTRL, RMASK, 0xF, false);
    return __int_as_float(r);
}

// ---------------------------------------------------------------------------
// Fused softmax + skewT with COALESCED skewT writes. 16 rows per block:
// wave w computes softmax of rows r0+4w..+3 (Pbf out) and stages the raw sim
// rows in LDS. Write phase: thread t -> (pc = t>>2 + 64*pass, quad = t&3);
// 4 consecutive lanes assemble skewT[pc][i0..i0+15] as one full 64B line
// (12 passes cover pc=0..767). off(i) = ((i>>2)&63) + 72*((i>>2)>>6); the 16
// rows are 4 quads with consecutive offs (same 64-block & same wave index
// since i0 % 16 == 0). Invalid (pc,quad) slots get 0.0f - never read (DTW
// jj<512 guard). skewT[b][pc][i] = sim[b][i][(pc - off(i)) mod 768].
// ---------------------------------------------------------------------------
__global__ __launch_bounds__(256) void softmax_skewT16_kernel(
    const float* __restrict__ sim, unsigned short* __restrict__ Pbf,
    float* __restrict__ skewT)
{
    __shared__ float tl[16][512];   // 32 KB
    const int wave = threadIdx.x >> 6;
    const int lane = threadIdx.x & 63;
    const int r0 = blockIdx.x * 16;
    const int b  = r0 >> 10;
    const int i0 = r0 & 1023;

    const float L2E = 1.44269504f;
    #pragma unroll
    for (int j = 0; j < 4; ++j) {
        const size_t r = (size_t)r0 + 4 * wave + j;
        const float* p = sim + r * V_DIM + lane * 8;
        float4 u = *(const float4*)p;
        float4 w = *(const float4*)(p + 4);
        float s[8] = {u.x,u.y,u.z,u.w,w.x,w.y,w.z,w.w};

        float m = s[0];
        #pragma unroll
        for (int k = 1; k < 8; ++k) m = fmaxf(m, s[k]);
        #pragma unroll
        for (int t = 1; t < 64; t <<= 1) m = fmaxf(m, __shfl_xor(m, t, 64));

        float ex[8];
        float e = 0.f;
        #pragma unroll
        for (int k = 0; k < 8; ++k) { ex[k] = exp2f((s[k] - m) * L2E); e += ex[k]; }
        #pragma unroll
        for (int t = 1; t < 64; t <<= 1) e += __shfl_xor(e, t, 64);
        const float ri = 1.0f / e;

        bf16x8 h;
        #pragma unroll
        for (int k = 0; k < 8; ++k) h[k] = bf16_rne(ex[k] * ri);
        *(bf16x8*)(Pbf + r * V_DIM + lane * 8) = h;

        #pragma unroll
        for (int k = 0; k < 8; ++k) tl[4*wave + j][lane * 8 + k] = s[k];
    }
    __syncthreads();

    const int g0   = i0 >> 2;
    const int off0 = (g0 & 63) + 72 * (g0 >> 6);
    const int q    = threadIdx.x & 3;
    const int pcb  = threadIdx.x >> 2;
    float* sbase = skewT + (size_t)b * SKT_W * 1024 + i0 + 4 * q;
    #pragma unroll
    for (int pass = 0; pass < 12; ++pass) {
        const int pc = pcb + pass * 64;
        int c = pc - (off0 + q); if (c < 0) c += SKT_W;
        float4 v = make_float4(0.f, 0.f, 0.f, 0.f);
        if (c < 512) v = make_float4(tl[4*q+0][c], tl[4*q+1][c], tl[4*q+2][c], tl[4*q+3][c]);
        *(float4*)(sbase + (size_t)pc * 1024) = v;
    }
}

// ---------------------------------------------------------------------------
// Fused PV GEMM + 256-lane batched-barrier wavefront DTW with COALESCED
// column loads (verbatim R8-verified structure, 82.7 us): lane g owns rows
// 4g..4g+3, off = (g&63) + 72*(g>>6); barrier once per 8-step batch; boundary
// rows via per-wave 520-slot LDS write-once arrays (NEG prefill, dump 519).
// ---------------------------------------------------------------------------
__global__ __launch_bounds__(256) void pv_dtw_kernel(
    const unsigned short* __restrict__ Pbf, const unsigned short* __restrict__ vTb,
    const float* __restrict__ skewT, float* __restrict__ out_aligned,
    float* __restrict__ out_score)
{
    __shared__ __align__(16) unsigned short lA[8*64*8];
    __shared__ __align__(16) unsigned short lB[8*64*8];

    if (blockIdx.x < 16) {
        // ---------------- DTW path (all 256 threads) ----------------
        const int b    = blockIdx.x;
        const int tid  = threadIdx.x;
        const int lane = tid & 63;
        const int wv   = tid >> 6;
        const int off  = lane + 72 * wv;

        float* bndAll = (float*)lA;                    // 3 x 520 floats
        float* bndP = bndAll + wv * 520;
        const float* bndC = bndAll + (wv > 0 ? wv - 1 : 0) * 520;
        for (int i = tid; i < 3 * 520; i += 256) bndAll[i] = NEGV;
        __syncthreads();

        const float* Sb = skewT + (size_t)b * SKT_W * 1024 + 4 * tid;

        float dp[4] = {NEGV, NEGV, NEGV, NEGV};
        float st[8];
        float upC = NEGV;
        float upL = (tid == 0) ? 0.0f : NEGV;

        float4 CA[8], CB[8];
        #pragma unroll
        for (int k = 0; k < 8; ++k) CA[k] = *(const float4*)(Sb + (size_t)k * 1024);
        #pragma unroll
        for (int k = 0; k < 8; ++k) CB[k] = *(const float4*)(Sb + (size_t)(k + 8) * 1024);

#define DTW_STEP(K, CK, FK)                                                   \
        {                                                                     \
            const unsigned jj = (unsigned)(sb + (K) - off);                   \
            if (jj < 512u) {                                                  \
                float u = upC, g = upL, old, nd;                              \
                old = dp[0]; nd = (CK).x + max3f(u, dp[0], g); dp[0] = nd; g = old; u = nd; \
                old = dp[1]; nd = (CK).y + max3f(u, dp[1], g); dp[1] = nd; g = old; u = nd; \
                old = dp[2]; nd = (CK).z + max3f(u, dp[2], g); dp[2] = nd; g = old; u = nd; \
                old = dp[3]; nd = (CK).w + max3f(u, dp[3], g); dp[3] = nd;                  \
            }                                                                 \
            st[K] = dp[3];                                                    \
            upL = upC;                                                        \
            upC = fdpp<0x138, 0xF>((FK), dp[3]);                              \
        }

#define DTW_BATCH(CC)                                                         \
        {                                                                     \
            float4 f0, f1;                                                    \
            const int ps = sb + 8 - 72 * wv;                                  \
            if (wv > 0 && ps >= 0 && ps <= 512) {                             \
                f0 = *(const float4*)&bndC[ps];                               \
                f1 = *(const float4*)&bndC[ps + 4];                           \
            } else {                                                          \
                f0 = make_float4(NEGV, NEGV, NEGV, NEGV); f1 = f0;            \
            }                                                                 \
            DTW_STEP(0, CC[0], f0.x) DTW_STEP(1, CC[1], f0.y)                 \
            DTW_STEP(2, CC[2], f0.z) DTW_STEP(3, CC[3], f0.w)                 \
            DTW_STEP(4, CC[4], f1.x) DTW_STEP(5, CC[5], f1.y)                 \
            DTW_STEP(6, CC[6], f1.z) DTW_STEP(7, CC[7], f1.w)                 \
            {                                                                 \
                _Pragma("unroll")                                             \
                for (int k = 0; k < 8; ++k) {                                 \
                    int cc_ = sb + 16 + k; if (cc_ >= SKT_W) cc_ -= SKT_W;    \
                    CC[k] = *(const float4*)(Sb + (size_t)cc_ * 1024);        \
                }                                                             \
            }                                                                 \
            if (wv < 3 && lane == 63) {                                       \
                _Pragma("unroll")                                             \
                for (int k = 0; k < 8; ++k) {                                 \
                    const int jp = sb + k - 63 - 72 * wv;                     \
                    const int adr = ((unsigned)jp < 512u) ? (jp + 7) : 519;   \
                    bndP[adr] = st[k];                                        \
                }                                                             \
            }                                                                 \
            asm volatile("s_waitcnt lgkmcnt(0)" ::: "memory");                \
            __builtin_amdgcn_s_barrier();                                     \
            asm volatile("" ::: "memory");                                    \
        }

        #pragma unroll 1
        for (int bt = 0; bt < 100; bt += 2) {
            int sb = bt * 8;
            DTW_BATCH(CA)
            sb += 8;
            DTW_BATCH(CB)
        }
#undef DTW_BATCH
#undef DTW_STEP
        if (tid == 255) out_score[b] = dp[3];   // row 1023, col 511
        return;
    }

    // ---------------- PV GEMM path ----------------
    const int bid = blockIdx.x - 16;
    const int n0 = (bid & 3) * 128;          // D/128 = 4
    const int m0 = ((bid >> 2) & 7) * 128;   // A/128 = 8
    const int bz = bid >> 5;                 // 16 batches

    const unsigned short* Ab = Pbf + (size_t)bz * A_DIM * V_DIM;
    const unsigned short* Bb = vTb + (size_t)bz * V_DIM * D_DIM;
    float*                Cb = out_aligned + (size_t)bz * A_DIM * D_DIM;

    gemm_tile_body(Ab, Bb, nullptr, Cb, m0, n0, V_DIM, D_DIM, threadIdx.x, lA, lB);
}

// ---------------------------------------------------------------------------
extern "C" void kernel_launch(void* const* d_in, const int* in_sizes, int n_in,
                              void* d_out, int out_size, void* d_ws, size_t ws_size,
                              hipStream_t stream)
{
    const float* audio = (const float*)d_in[0];   // [16,1024,512]
    const float* video = (const float*)d_in[1];   // [16, 512,512]
    const float* W     = (const float*)d_in[2];   // [512,512]
    const float* bias  = (const float*)d_in[3];   // [512]

    float* out_aligned = (float*)d_out;
    float* out_score   = (float*)d_out + (size_t)B_DIM * A_DIM * D_DIM;

    const size_t NA = (size_t)B_DIM * A_DIM * D_DIM;   // 8.39M
    const size_t NV = (size_t)B_DIM * V_DIM * D_DIM;   // 4.19M
    const size_t NS = (size_t)B_DIM * A_DIM * V_DIM;   // 8.39M

    float* ws = (float*)d_ws;
    float*          a_p  = ws;                                 // NA fp32 [dead after norm-a]
    float*          v_p  = a_p + NA;                           // NV fp32 [dead after norm-v]
    float*          sim  = v_p + NV;                           // NS fp32
    unsigned short* abf  = (unsigned short*)(sim + NS);        // NA bf16 [dead after proj-a]
    unsigned short* vbf  = (unsigned short*)(sim + NS) + NA;   // NV bf16 [dead after proj-v]
    unsigned short* v_nb = vbf + NV;                           // NV bf16
    unsigned short* Wbf  = v_nb + NV;                          // 262144 bf16
    unsigned short* a_nb = abf;            // NA bf16 reuses dead abf (norm-a)
    unsigned short* Pbf  = abf;            // NS bf16 reuses a_nb (dead after sim GEMM)
    unsigned short* vTb  = vbf;            // NV bf16 reuses dead vbf
    // skewT: 16 x 768 x 1024 fp32 = 12.58M floats = a_p + v_p exactly.
    float*          skewT = a_p;

    // 1) fp32 -> bf16 input conversions, one merged launch
    {
        const int nb_a = (int)(NA / 8 / 256);             // 4096
        const int nb_v = (int)(NV / 8 / 256);             // 2048
        const int nb_w = D_DIM * D_DIM / 8 / 256;         // 128
        cvt3_bf16_kernel<<<dim3(nb_a + nb_v + nb_w), dim3(256), 0, stream>>>(
            audio, abf, nb_a, video, vbf, nb_v, W, Wbf);
    }

    // 2) merged projections: audio & video X @ W^T + b
    gemm_proj2<<<dim3(D_DIM/128, 192), dim3(256), 0, stream>>>(
        abf, vbf, Wbf, bias, a_p, v_p);

    // 3) merged rownorm-a + rownorm-v + video transpose
    norm2_transpose_kernel<<<dim3(4096 + 2048 + 4096), dim3(256), 0, stream>>>(
        a_p, a_nb, v_p, v_nb, video, vTb);

    // 4) sim[b] = a_n[b] @ v_n[b]^T
    gemm_bf16_nt<<<dim3(V_DIM/128, A_DIM/128, B_DIM), dim3(256), 0, stream>>>(
        a_nb, v_nb, nullptr, sim, A_DIM, V_DIM, D_DIM,
        (size_t)A_DIM*D_DIM, (size_t)V_DIM*D_DIM, (size_t)A_DIM*V_DIM);

    // 5) fused row softmax -> Pbf + coalesced column-major skewT (16 rows/blk)
    softmax_skewT16_kernel<<<dim3((B_DIM*A_DIM)/16), dim3(256), 0, stream>>>(
        sim, Pbf, skewT);

    // 6) fused PV GEMM + 4-wave batched coalesced DTW (R8-verified)
    pv_dtw_kernel<<<dim3(16 + (D_DIM/128)*(A_DIM/128)*B_DIM), dim3(256), 0, stream>>>(
        Pbf, vTb, skewT, out_aligned, out_score);
}